// Round 18
// baseline (2717.964 us; speedup 1.0000x reference)
//
#include <hip/hip_runtime.h>
#include <hip/hip_bf16.h>
#include <math.h>
#include <cstdint>

// ---------------- problem constants ----------------
constexpr int Bn   = 32;
constexpr int Dn   = 768;
constexpr int NHn  = 12;
constexpr int HDn  = 64;
constexpr int Ln   = 12;
constexpr int DFFn = 3072;
constexpr int OUTn = 1000;
constexpr int Sn   = 197;          // 14*14 + 1 tokens
constexpr int Mrows = Bn * Sn;     // 6304
constexpr int NPATCH = 196;

typedef __attribute__((ext_vector_type(8))) short bf16x8;
typedef __attribute__((ext_vector_type(4))) float f32x4;

__device__ inline void store_val(float* p, float v) { *p = v; }
__device__ inline void store_val(__hip_bfloat16* p, float v) { *p = __float2bfloat16(v); }
__device__ inline short f2bs(float f) {
  __hip_bfloat16 h = __float2bfloat16(f);
  return __builtin_bit_cast(short, h);
}

// async global->LDS, 16B per lane; LDS dest = wave-uniform base + lane*16
__device__ inline void gload_lds16(const void* g, void* l) {
  auto gp = (const __attribute__((address_space(1))) unsigned int*)(uintptr_t)g;
  auto lp = (__attribute__((address_space(3))) unsigned int*)(uintptr_t)l;
  __builtin_amdgcn_global_load_lds(gp, lp, 16, 0, 0);
}

// bijective XCD-chunk swizzle (m204)
__device__ inline int xcd_swizzle(int orig, int nwg) {
  const int xcd = orig & 7, local = orig >> 3;
  const int q = nwg >> 3, r = nwg & 7;
  return (xcd < r) ? xcd * (q + 1) + local : r * (q + 1) + (xcd - r) * q + local;
}

// ---------------- bf16 MFMA GEMM: 128x128, 3-buffer ring, counted vmcnt ----------------
template<int ACT, bool RES, int SPLITK, typename OT>   // ACT: 0 none, 1 gelu
__global__ __launch_bounds__(256) void bgemm_kernel(
    const __hip_bfloat16* __restrict__ A,
    const __hip_bfloat16* __restrict__ Bt,
    const float* __restrict__ bias,
    const float* __restrict__ res,
    OT* __restrict__ out, int M, int N, int K, int kloop)
{
  __shared__ __hip_bfloat16 As[3][128 * 32];   // 3 x 8 KB
  __shared__ __hip_bfloat16 Bs[3][128 * 32];
  const int tid  = threadIdx.x;
  const int w    = tid >> 6, lane = tid & 63;
  const int wm   = w >> 1,   wn   = w & 1;
  const int kg   = lane >> 4, fr = lane & 15;

  if (SPLITK) {
    const int koff = blockIdx.z * kloop;
    A  += koff;
    Bt += koff;
    out += (size_t)blockIdx.z * M * N;
  }

  const int nwg = gridDim.x * gridDim.y;
  const int wg  = xcd_swizzle(blockIdx.y * gridDim.x + blockIdx.x, nwg);
  const int bm  = (wg / gridDim.x) * 128;
  const int bn  = (wg % gridDim.x) * 128;

  const int obase0 = w * 2048;
  const int obase1 = w * 2048 + 1024;
  const int o0 = obase0 + lane * 16, o1 = obase1 + lane * 16;
  const int r0 = o0 >> 6,            r1 = o1 >> 6;
  const int ks0 = (((o0 >> 4) & 3) ^ ((r0 >> 1) & 3)) * 8;
  const int ks1 = (((o1 >> 4) & 3) ^ ((r1 >> 1) & 3)) * 8;
  const int ga0 = (bm + r0 >= M) ? M - 1 : bm + r0;
  const int ga1 = (bm + r1 >= M) ? M - 1 : bm + r1;
  const int gb0 = bn + r0, gb1 = bn + r1;

  f32x4 acc[4][4];
  #pragma unroll
  for (int i = 0; i < 4; ++i)
    #pragma unroll
    for (int j = 0; j < 4; ++j) acc[i][j] = (f32x4)(0.f);

  const int nt = kloop >> 5;

  auto STAGE = [&](int t, int bi) {
    const int k0 = t << 5;
    gload_lds16(A  + (size_t)ga0 * K + k0 + ks0, (char*)As[bi] + obase0);
    gload_lds16(A  + (size_t)ga1 * K + k0 + ks1, (char*)As[bi] + obase1);
    gload_lds16(Bt + (size_t)gb0 * K + k0 + ks0, (char*)Bs[bi] + obase0);
    gload_lds16(Bt + (size_t)gb1 * K + k0 + ks1, (char*)Bs[bi] + obase1);
  };
  auto COMPUTE = [&](int bi) {
    bf16x8 af[4], bfv[4];
    #pragma unroll
    for (int tt = 0; tt < 4; ++tt) {
      const int r = wm * 64 + tt * 16 + fr;
      af[tt]  = *(const bf16x8*)((const char*)As[bi] + r * 64 + ((kg ^ ((r >> 1) & 3)) << 4));
      const int c = wn * 64 + tt * 16 + fr;
      bfv[tt] = *(const bf16x8*)((const char*)Bs[bi] + c * 64 + ((kg ^ ((c >> 1) & 3)) << 4));
    }
    #pragma unroll
    for (int mt = 0; mt < 4; ++mt)
      #pragma unroll
      for (int nt2 = 0; nt2 < 4; ++nt2)
        acc[mt][nt2] = __builtin_amdgcn_mfma_f32_16x16x32_bf16(af[mt], bfv[nt2], acc[mt][nt2], 0, 0, 0);
  };

  STAGE(0, 0);
  STAGE(1, 1);

  int cur = 0;
  for (int t = 0; t < nt - 1; ++t) {
    asm volatile("s_waitcnt vmcnt(4)" ::: "memory");
    __builtin_amdgcn_s_barrier();
    __builtin_amdgcn_sched_barrier(0);
    if (t + 2 < nt) {
      int nb = cur + 2; if (nb >= 3) nb -= 3;
      STAGE(t + 2, nb);
    }
    COMPUTE(cur);
    ++cur; if (cur == 3) cur = 0;
  }
  asm volatile("s_waitcnt vmcnt(0)" ::: "memory");
  __builtin_amdgcn_s_barrier();
  __builtin_amdgcn_sched_barrier(0);
  COMPUTE(cur);

  #pragma unroll
  for (int nt2 = 0; nt2 < 4; ++nt2) {
    const int cb = bn + wn * 64 + nt2 * 16 + fr;
    const float bs = SPLITK ? 0.f : bias[cb];
    #pragma unroll
    for (int mt = 0; mt < 4; ++mt) {
      #pragma unroll
      for (int j = 0; j < 4; ++j) {
        const int rb = bm + wm * 64 + mt * 16 + kg * 4 + j;
        if (rb >= M) continue;
        float v = acc[mt][nt2][j] + bs;
        if (ACT == 1) v = 0.5f * v * (1.f + erff(v * 0.70710678118654752f));
        if (RES) v += res[(size_t)rb * N + cb];
        store_val(out + (size_t)rb * N + cb, v);
      }
    }
  }
}

// ---------------- split-K reduce: h += p0 + p1 + bias (elementwise) ----------------
__global__ __launch_bounds__(256) void redk_kernel(const float* __restrict__ p0,
                                                   const float* __restrict__ p1,
                                                   const float* __restrict__ bias,
                                                   float* __restrict__ h, int n4)
{
  const int i = blockIdx.x * 256 + threadIdx.x;
  if (i >= n4) return;
  const float4 a = ((const float4*)p0)[i];
  const float4 b = ((const float4*)p1)[i];
  const float4 r = ((const float4*)h)[i];
  const float4 bs = ((const float4*)bias)[i % (Dn / 4)];
  float4 o;
  o.x = r.x + a.x + b.x + bs.x;
  o.y = r.y + a.y + b.y + bs.y;
  o.z = r.z + a.z + b.z + bs.z;
  o.w = r.w + a.w + b.w + bs.w;
  ((float4*)h)[i] = o;
}

// ---------------- fused split-K reduce + LayerNorm ----------------
__global__ __launch_bounds__(256) void redk_ln_kernel(
    const float* __restrict__ p0, const float* __restrict__ p1,
    const float* __restrict__ bias, float* __restrict__ h,
    const float* __restrict__ g, const float* __restrict__ bt,
    __hip_bfloat16* __restrict__ y)
{
  const int row = blockIdx.x;
  const int tid = threadIdx.x;
  const size_t base = (size_t)row * Dn;
  float hv[3];
  #pragma unroll
  for (int i = 0; i < 3; ++i) {
    const int c = tid + i * 256;
    const size_t idx = base + c;
    hv[i] = h[idx] + p0[idx] + p1[idx] + bias[c];
    h[idx] = hv[i];
  }
  float s = hv[0] + hv[1] + hv[2];
  float q = hv[0] * hv[0] + hv[1] * hv[1] + hv[2] * hv[2];
  #pragma unroll
  for (int o = 32; o > 0; o >>= 1) { s += __shfl_down(s, o); q += __shfl_down(q, o); }
  __shared__ float sa[4], sb[4];
  const int w = tid >> 6, lane = tid & 63;
  if (lane == 0) { sa[w] = s; sb[w] = q; }
  __syncthreads();
  if (tid == 0) {
    sa[0] = sa[0] + sa[1] + sa[2] + sa[3];
    sb[0] = sb[0] + sb[1] + sb[2] + sb[3];
  }
  __syncthreads();
  s = sa[0]; q = sb[0];
  const float mean = s * (1.f / 768.f);
  const float var  = q * (1.f / 768.f) - mean * mean;
  const float inv  = rsqrtf(var + 1e-5f);
  __hip_bfloat16* yr = y + base;
  #pragma unroll
  for (int i = 0; i < 3; ++i) {
    const int c = tid + i * 256;
    yr[c] = __float2bfloat16((hv[i] - mean) * inv * g[c] + bt[c]);
  }
}

// ---------------- bf16 MFMA GEMM: 128x256, 8 waves, 3-ring, counted vmcnt ----------------
template<int ACT, bool RES, typename OT>
__global__ __launch_bounds__(512) void wgemm_kernel(
    const __hip_bfloat16* __restrict__ A,
    const __hip_bfloat16* __restrict__ Bt,
    const float* __restrict__ bias,
    const float* __restrict__ res,
    OT* __restrict__ out, int M, int N, int K)
{
  constexpr int BUFSZ = 24576;
  __shared__ __align__(16) char lds[3 * BUFSZ];   // 72 KB
  const int tid  = threadIdx.x;
  const int wid  = tid >> 6, lane = tid & 63;
  const int wm   = wid >> 2, wn = wid & 3;        // 2M x 4N waves
  const int kg   = lane >> 4, fr = lane & 15;
  const int rs   = lane >> 2;                     // row within 16-row chunk
  const int ks   = (((lane & 3) ^ ((lane >> 3) & 3)) << 3);  // pre-swizzled k-elems

  const int gx  = gridDim.x;
  const int nwg = gx * gridDim.y;
  const int wg  = xcd_swizzle(blockIdx.y * gx + blockIdx.x, nwg);
  const int bm  = (wg / gx) * 128;
  const int bn  = (wg % gx) * 256;

  f32x4 acc[4][4];
  #pragma unroll
  for (int i = 0; i < 4; ++i)
    #pragma unroll
    for (int j = 0; j < 4; ++j) acc[i][j] = (f32x4)(0.f);

  const int nt = K >> 5;

  auto STAGE = [&](int t) {
    const int k0 = t << 5;
    char* buf = lds + (t % 3) * BUFSZ;
    #pragma unroll
    for (int j = 0; j < 3; ++j) {
      const int c = wid + j * 8;                  // 0..23
      const __hip_bfloat16* src;
      if (c < 8) {                                // A chunk: tile rows c*16..+15
        int gr = bm + c * 16 + rs; if (gr >= M) gr = M - 1;
        src = A + (size_t)gr * K + k0 + ks;
      } else {                                    // B chunk: tile cols (c-8)*16..+15
        const int gc = bn + (c - 8) * 16 + rs;    // N multiple of 256 here
        src = Bt + (size_t)gc * K + k0 + ks;
      }
      gload_lds16(src, buf + c * 1024);           // wave-uniform base + lane*16
    }
  };
  auto COMPUTE = [&](int t) {
    const char* buf = lds + (t % 3) * BUFSZ;
    bf16x8 af[4], bfv[4];
    #pragma unroll
    for (int tt = 0; tt < 4; ++tt) {
      const int r = wm * 64 + tt * 16 + fr;       // 0..127
      af[tt]  = *(const bf16x8*)(buf + r * 64 + ((kg ^ ((r >> 1) & 3)) << 4));
      const int c = wn * 64 + tt * 16 + fr;       // 0..255
      bfv[tt] = *(const bf16x8*)(buf + 8192 + c * 64 + ((kg ^ ((c >> 1) & 3)) << 4));
    }
    #pragma unroll
    for (int mt = 0; mt < 4; ++mt)
      #pragma unroll
      for (int nt2 = 0; nt2 < 4; ++nt2)
        acc[mt][nt2] = __builtin_amdgcn_mfma_f32_16x16x32_bf16(af[mt], bfv[nt2], acc[mt][nt2], 0, 0, 0);
  };

  STAGE(0);
  STAGE(1);

  for (int t = 0; t < nt - 1; ++t) {
    asm volatile("s_waitcnt vmcnt(3)" ::: "memory");
    __builtin_amdgcn_s_barrier();
    __builtin_amdgcn_sched_barrier(0);
    if (t + 2 < nt) STAGE(t + 2);
    COMPUTE(t);
  }
  asm volatile("s_waitcnt vmcnt(0)" ::: "memory");
  __builtin_amdgcn_s_barrier();
  __builtin_amdgcn_sched_barrier(0);
  COMPUTE(nt - 1);

  if constexpr (sizeof(OT) == 2) {
    // bf16 output: repack through LDS so global stores are full-line 16B/lane.
    __syncthreads();
    short* ct = (short*)lds;                      // [128][256]
    #pragma unroll
    for (int fj = 0; fj < 4; ++fj) {
      const int col = wn * 64 + fj * 16 + fr;
      const float bs = bias[bn + col];
      #pragma unroll
      for (int fi = 0; fi < 4; ++fi)
        #pragma unroll
        for (int j = 0; j < 4; ++j) {
          const int row = wm * 64 + fi * 16 + kg * 4 + j;
          float v = acc[fi][fj][j] + bs;
          if (ACT == 1) v = 0.5f * v * (1.f + erff(v * 0.70710678118654752f));
          ct[row * 256 + col] = f2bs(v);
        }
    }
    __syncthreads();
    #pragma unroll
    for (int c = 0; c < 8; ++c) {
      const int chunk = tid + c * 512;            // 0..4095
      const int row = chunk >> 5, ce = (chunk & 31) * 8;
      const int grow = bm + row;
      if (grow < M)
        *(bf16x8*)((short*)out + (size_t)grow * N + bn + ce) =
            *(const bf16x8*)(ct + row * 256 + ce);
    }
  } else {
    #pragma unroll
    for (int fj = 0; fj < 4; ++fj) {
      const int col = bn + wn * 64 + fj * 16 + fr;
      const float bs = bias[col];
      #pragma unroll
      for (int fi = 0; fi < 4; ++fi) {
        #pragma unroll
        for (int j = 0; j < 4; ++j) {
          const int row = bm + wm * 64 + fi * 16 + kg * 4 + j;
          if (row >= M) continue;
          float v = acc[fi][fj][j] + bs;
          if (ACT == 1) v = 0.5f * v * (1.f + erff(v * 0.70710678118654752f));
          if (RES) v += res[(size_t)row * N + col];
          store_val(out + (size_t)row * N + col, v);
        }
      }
    }
  }
}

// ---------------- transpose-convert: W[z][K,N] fp32 -> Wt[z][N,K] bf16 (guarded) ----------------
__global__ __launch_bounds__(256) void convT_kernel(const float* __restrict__ W,
                                                    __hip_bfloat16* __restrict__ Wt,
                                                    int K, int N)
{
  const size_t lw = (size_t)K * N;
  const float* Wb = W + blockIdx.z * lw;
  __hip_bfloat16* Wo = Wt + blockIdx.z * lw;
  __shared__ float t[32][33];
  const int k0 = blockIdx.y * 32, n0 = blockIdx.x * 32;
  const int r  = threadIdx.x >> 3, c4 = (threadIdx.x & 7) * 4;
  const float* wp = Wb + (size_t)(k0 + r) * N + n0 + c4;
  float4 v = make_float4(0.f, 0.f, 0.f, 0.f);
  if (n0 + c4 + 3 < N) v = *(const float4*)wp;
  else {
    if (n0 + c4 + 0 < N) v.x = wp[0];
    if (n0 + c4 + 1 < N) v.y = wp[1];
    if (n0 + c4 + 2 < N) v.z = wp[2];
  }
  t[r][c4 + 0] = v.x; t[r][c4 + 1] = v.y; t[r][c4 + 2] = v.z; t[r][c4 + 3] = v.w;
  __syncthreads();
  const int n = n0 + r;
  if (n < N) {
    __hip_bfloat16* o = Wo + (size_t)n * K + k0 + c4;
    o[0] = __float2bfloat16(t[c4 + 0][r]);
    o[1] = __float2bfloat16(t[c4 + 1][r]);
    o[2] = __float2bfloat16(t[c4 + 2][r]);
    o[3] = __float2bfloat16(t[c4 + 3][r]);
  }
}

// ---------------- head GEMV: out[32,N] = act(A[32,K] @ Wt[N,K]^T + bias) ----------------
template<int ACT>   // 0 none, 2 tanh
__global__ __launch_bounds__(256) void hgemv_kernel(
    const float* __restrict__ A, const __hip_bfloat16* __restrict__ Wt,
    const float* __restrict__ bias, float* __restrict__ out, int N, int K)
{
  const int w = threadIdx.x >> 6, lane = threadIdx.x & 63;
  const int e = blockIdx.x * 4 + w;
  const int m = e & 31, n = e >> 5;
  if (n >= N) return;
  const float* a = A + (size_t)m * K;
  const __hip_bfloat16* wr = Wt + (size_t)n * K;
  float s = 0.f;
  for (int k = lane; k < K; k += 64)
    s = fmaf(a[k], __bfloat162float(wr[k]), s);
  #pragma unroll
  for (int o = 32; o > 0; o >>= 1) s += __shfl_xor(s, o);
  if (lane == 0) {
    float v = s + bias[n];
    if (ACT == 2) v = tanhf(v);
    out[(size_t)m * N + n] = v;
  }
}

// ---------------- patchify: x[B,C,224,224] -> patches[B*196, 768] bf16 ----------------
__global__ __launch_bounds__(256) void patchify_kernel(const float* __restrict__ x,
                                                       __hip_bfloat16* __restrict__ p)
{
  size_t i = (size_t)blockIdx.x * 256 + threadIdx.x;
  constexpr size_t total = (size_t)Bn * NPATCH * 768;
  if (i >= total) return;
  int k = (int)(i % 768);
  size_t m = i / 768;
  int b = (int)(m / NPATCH), pp = (int)(m % NPATCH);
  int py = pp / 14, px = pp % 14;
  int c = k >> 8, ph = (k >> 4) & 15, pw = k & 15;
  p[i] = __float2bfloat16(x[(((size_t)(b * 3 + c)) * 224 + py * 16 + ph) * 224 + px * 16 + pw]);
}

// ---------------- assemble: tokens+cls+pos -> [B,S,D] fp32 ----------------
__global__ __launch_bounds__(256) void assemble_kernel(const float* __restrict__ tok,
                                                       const float* __restrict__ cls,
                                                       const float* __restrict__ pos,
                                                       float* __restrict__ outp)
{
  size_t i = (size_t)blockIdx.x * 256 + threadIdx.x;
  constexpr size_t total = (size_t)Bn * Sn * Dn;
  if (i >= total) return;
  int d = (int)(i % Dn);
  size_t m = i / Dn;
  int s = (int)(m % Sn);
  size_t b = m / Sn;
  float v = (s == 0) ? cls[d] : tok[(b * NPATCH + (s - 1)) * Dn + d];
  outp[i] = v + pos[s * Dn + d];
}

// ---------------- LayerNorm over D=768, one block per row ----------------
template<typename OT>
__global__ __launch_bounds__(256) void ln_kernel(const float* __restrict__ x, size_t xstride,
                                                 const float* __restrict__ g,
                                                 const float* __restrict__ bt,
                                                 OT* __restrict__ out)
{
  const int row = blockIdx.x;
  const int tid = threadIdx.x;
  const float* xr = x + (size_t)row * xstride;
  float v0 = xr[tid], v1 = xr[tid + 256], v2 = xr[tid + 512];
  float s = v0 + v1 + v2;
  float q = v0 * v0 + v1 * v1 + v2 * v2;
  #pragma unroll
  for (int o = 32; o > 0; o >>= 1) { s += __shfl_down(s, o); q += __shfl_down(q, o); }
  __shared__ float sa[4], sb[4];
  int w = tid >> 6, lane = tid & 63;
  if (lane == 0) { sa[w] = s; sb[w] = q; }
  __syncthreads();
  if (tid == 0) {
    float ts = sa[0] + sa[1] + sa[2] + sa[3];
    float tq = sb[0] + sb[1] + sb[2] + sb[3];
    sa[0] = ts; sb[0] = tq;
  }
  __syncthreads();
  s = sa[0]; q = sb[0];
  const float mean = s * (1.f / 768.f);
  const float var  = q * (1.f / 768.f) - mean * mean;
  const float inv  = rsqrtf(var + 1e-5f);
  OT* orow = out + (size_t)row * Dn;
  store_val(orow + tid,       (v0 - mean) * inv * g[tid]       + bt[tid]);
  store_val(orow + tid + 256, (v1 - mean) * inv * g[tid + 256] + bt[tid + 256]);
  store_val(orow + tid + 512, (v2 - mean) * inv * g[tid + 512] + bt[tid + 512]);
}

// ---------------- MFMA flash attention (Q-split x2, KV-chunked, 3 blocks/CU) ----------------
// LDS 42 KB: K chunk [<=128][64], V^T chunk [64][136], Pl per-wave [32][32].
// 768 blocks all resident at 3 blocks/CU -> no tail imbalance.
__global__ __launch_bounds__(256) void attn_mfma_kernel(
    const __hip_bfloat16* __restrict__ qkv, __hip_bfloat16* __restrict__ ctx)
{
  const int bh = blockIdx.x >> 1, qh = blockIdx.x & 1;
  const int b = bh / NHn, h = bh % NHn;
  const int tid = threadIdx.x;
  const int w = tid >> 6, lane = tid & 63;
  const int kg = lane >> 4, fr = lane & 15;

  __shared__ short Kl[128 * 64];       // 16 KB (max 128-key chunk)
  __shared__ short Vt[64 * 136];       // 17.4 KB
  __shared__ short Pl[4 * 1024];       // 8 KB, per-wave [32][32]

  const size_t rstr = 3 * (size_t)Dn;  // 2304
  const __hip_bfloat16* base = qkv + (size_t)b * Sn * rstr;

  // Q fragments: this block's 128 rows = qh*128 + w*32 ..
  const int qw = qh * 128 + w * 32;
  bf16x8 qf[2][2];
  #pragma unroll
  for (int qt = 0; qt < 2; ++qt)
    #pragma unroll
    for (int kk = 0; kk < 2; ++kk) {
      int q = qw + qt * 16 + fr; if (q >= Sn) q = Sn - 1;
      qf[qt][kk] = *(const bf16x8*)(base + (size_t)q * rstr + h * HDn + kk * 32 + kg * 8);
    }

  float mold[2][4], lsum[2][4];
  f32x4 cacc[2][4];
  #pragma unroll
  for (int qt = 0; qt < 2; ++qt)
    #pragma unroll
    for (int j = 0; j < 4; ++j) {
      mold[qt][j] = -1e30f; lsum[qt][j] = 0.f;
      cacc[qt][j] = (f32x4)(0.f);
    }
  const float scale = 0.125f;

  for (int ch = 0; ch < 2; ++ch) {
    const int kbase = ch * 128;
    const int nit = ch ? 3 : 4;        // chunk keys = nit*32 (128 then 96)
    __syncthreads();                   // all waves done reading previous chunk
    // stage K chunk (async direct-to-LDS, slot-swizzled source)
    for (int it = 0; it < nit; ++it) {
      const int i = it * 256 + tid;
      const int r = i >> 3, s = i & 7;
      const int rr = (kbase + r < Sn) ? kbase + r : Sn - 1;
      gload_lds16(base + (size_t)rr * rstr + Dn + h * HDn + ((s ^ (r & 7)) << 3),
                  (char*)Kl + it * 4096 + w * 1024);
    }
    // stage V^T chunk (reg->LDS transpose)
    for (int it = 0; it < nit; ++it) {
      const int i = it * 256 + tid;
      const int key = i >> 3, d0 = (i & 7) * 8;
      const int rr = (kbase + key < Sn) ? kbase + key : Sn - 1;
      bf16x8 v = *(const bf16x8*)(base + (size_t)rr * rstr + 2 * Dn + h * HDn + d0);
      #pragma unroll
      for (int e = 0; e < 8; ++e) Vt[(d0 + e) * 136 + key] = v[e];
    }
    __syncthreads();

    const int nk = nit * 32;
    for (int kc = 0; kc < nk; kc += 32) {
      f32x4 sacc[2][2];
      #pragma unroll
      for (int qt = 0; qt < 2; ++qt) { sacc[qt][0] = (f32x4)(0.f); sacc[qt][1] = (f32x4)(0.f); }
      #pragma unroll
      for (int nt = 0; nt < 2; ++nt) {
        const int key = kc + nt * 16 + fr;   // local to chunk
        const bf16x8 kf0 = *(const bf16x8*)((const char*)Kl + key * 128 + ((kg ^ (key & 7)) << 4));
        const bf16x8 kf1 = *(const bf16x8*)((const char*)Kl + key * 128 + (((4 + kg) ^ (key & 7)) << 4));
        #pragma unroll
        for (int qt = 0; qt < 2; ++qt) {
          sacc[qt][nt] = __builtin_amdgcn_mfma_f32_16x16x32_bf16(qf[qt][0], kf0, sacc[qt][nt], 0, 0, 0);
          sacc[qt][nt] = __builtin_amdgcn_mfma_f32_16x16x32_bf16(qf[qt][1], kf1, sacc[qt][nt], 0, 0, 0);
        }
      }
      const float madd0 = (kbase + kc + fr < Sn) ? 0.f : -3e38f;
      const float madd1 = (kbase + kc + 16 + fr < Sn) ? 0.f : -3e38f;
      #pragma unroll
      for (int qt = 0; qt < 2; ++qt) {
        sacc[qt][0] = sacc[qt][0] * scale + (f32x4)(madd0);
        sacc[qt][1] = sacc[qt][1] * scale + (f32x4)(madd1);
      }
      #pragma unroll
      for (int qt = 0; qt < 2; ++qt) {
        #pragma unroll
        for (int j = 0; j < 4; ++j) {
          float t = fmaxf(sacc[qt][0][j], sacc[qt][1][j]);
          t = fmaxf(t, __shfl_xor(t, 1));
          t = fmaxf(t, __shfl_xor(t, 2));
          t = fmaxf(t, __shfl_xor(t, 4));
          t = fmaxf(t, __shfl_xor(t, 8));
          const float mn = fmaxf(mold[qt][j], t);
          const float corr = __expf(mold[qt][j] - mn);
          mold[qt][j] = mn;
          const float p0 = __expf(sacc[qt][0][j] - mn);
          const float p1 = __expf(sacc[qt][1][j] - mn);
          sacc[qt][0][j] = p0; sacc[qt][1][j] = p1;
          float ps = p0 + p1;
          ps += __shfl_xor(ps, 1); ps += __shfl_xor(ps, 2);
          ps += __shfl_xor(ps, 4); ps += __shfl_xor(ps, 8);
          lsum[qt][j] = lsum[qt][j] * corr + ps;
          #pragma unroll
          for (int ht = 0; ht < 4; ++ht) cacc[qt][ht][j] *= corr;
        }
        #pragma unroll
        for (int nt = 0; nt < 2; ++nt) {
          const int c = nt * 16 + fr;
          #pragma unroll
          for (int j = 0; j < 4; ++j) {
            const int r = qt * 16 + kg * 4 + j;
            Pl[w * 1024 + r * 32 + (((c >> 3) ^ (r & 3)) << 3) + (c & 7)] = f2bs(sacc[qt][nt][j]);
          }
        }
      }
      bf16x8 vf[4];
      #pragma unroll
      for (int ht = 0; ht < 4; ++ht)
        vf[ht] = *(const bf16x8*)(Vt + (ht * 16 + fr) * 136 + kc + kg * 8);
      #pragma unroll
      for (int qt = 0; qt < 2; ++qt) {
        const int r = qt * 16 + fr;
        const bf16x8 pf = *(const bf16x8*)(Pl + w * 1024 + r * 32 + ((kg ^ (r & 3)) << 3));
        #pragma unroll
        for (int ht = 0; ht < 4; ++ht)
          cacc[qt][ht] = __builtin_amdgcn_mfma_f32_16x16x32_bf16(pf, vf[ht], cacc[qt][ht], 0, 0, 0);
      }
    }
  }
  __hip_bfloat16* cb = ctx + (size_t)b * Sn * Dn + h * HDn;
  #pragma unroll
  for (int qt = 0; qt < 2; ++qt)
    #pragma unroll
    for (int j = 0; j < 4; ++j) {
      const int q = qw + qt * 16 + kg * 4 + j;
      if (q < Sn) {
        const float inv = 1.f / lsum[qt][j];
        #pragma unroll
        for (int ht = 0; ht < 4; ++ht)
          cb[(size_t)q * Dn + ht * 16 + fr] = __float2bfloat16(cacc[qt][ht][j] * inv);
      }
    }
}

// ---------------- host side ----------------
using bf16 = __hip_bfloat16;

static inline void run_convT(const float* W, bf16* Wt, int K, int N, int L, hipStream_t st) {
  convT_kernel<<<dim3((N + 31) / 32, K / 32, L), 256, 0, st>>>(W, Wt, K, N);
}

extern "C" void kernel_launch(void* const* d_in, const int* in_sizes, int n_in,
                              void* d_out, int out_size, void* d_ws, size_t ws_size,
                              hipStream_t stream)
{
  const float* x      = (const float*)d_in[0];
  const float* emb_w  = (const float*)d_in[1];
  const float* emb_b  = (const float*)d_in[2];
  const float* cls    = (const float*)d_in[3];
  const float* pos    = (const float*)d_in[4];
  const float* pre_g  = (const float*)d_in[5];
  const float* pre_b  = (const float*)d_in[6];
  const float* ln1_g  = (const float*)d_in[7];
  const float* ln1_b  = (const float*)d_in[8];
  const float* qkv_w  = (const float*)d_in[9];
  const float* qkv_b  = (const float*)d_in[10];
  const float* proj_w = (const float*)d_in[11];
  const float* proj_b = (const float*)d_in[12];
  const float* ln2_g  = (const float*)d_in[13];
  const float* ln2_b  = (const float*)d_in[14];
  const float* fc1_w  = (const float*)d_in[15];
  const float* fc1_b  = (const float*)d_in[16];
  const float* fc2_w  = (const float*)d_in[17];
  const float* fc2_b  = (const float*)d_in[18];
  const float* post_g = (const float*)d_in[19];
  const float* post_b = (const float*)d_in[20];
  const float* h1_w   = (const float*)d_in[21];
  const float* h1_b   = (const float*)d_in[22];
  const float* h2_w   = (const float*)d_in[23];
  const float* h2_b   = (const float*)d_in[24];
  float* out = (float*)d_out;

  // workspace layout
  const size_t HN = (size_t)Mrows * Dn;
  float* hbuf = (float*)d_ws;                         // fp32 residual [M,768]
  bf16*  qkvb = (bf16*)(hbuf + HN);                   // bf16 [M,2304]; also fp32 staging
  bf16*  abf1 = qkvb + (size_t)Mrows * 3 * Dn;        // bf16 [M,768]
  bf16*  abf2 = abf1 + HN;                            // bf16 [M,3072]; also fp32 staging
  bf16*  wtb  = abf2 + (size_t)Mrows * DFFn;          // bf16 scratch Wt (max 2304x768)

  // optional pre-converted all-layer weights (bf16, transposed)
  bf16* bigq = wtb + (size_t)2304 * 768;
  bf16* bigp = bigq + (size_t)Ln * 3 * Dn * Dn;
  bf16* big1 = bigp + (size_t)Ln * Dn * Dn;
  bf16* big2 = big1 + (size_t)Ln * Dn * DFFn;
  bf16* endBig = big2 + (size_t)Ln * DFFn * Dn;
  const size_t need_big = (size_t)((char*)endBig - (char*)d_ws);
  const bool useBig = ws_size >= need_big;

  // split-K partials: two contiguous fp32 planes of HN at endBig.
  float* skp1 = (float*)endBig;
  const size_t need_split = need_big + 2 * HN * sizeof(float);
  const bool useSplit = useBig && ws_size >= need_split;

  const int gM = (Mrows + 127) / 128;                 // 50

  if (useBig) {
    run_convT(qkv_w,  bigq, Dn, 3 * Dn, Ln, stream);
    run_convT(proj_w, bigp, Dn, Dn,     Ln, stream);
    run_convT(fc1_w,  big1, Dn, DFFn,   Ln, stream);
    run_convT(fc2_w,  big2, DFFn, Dn,   Ln, stream);
  }

  // 1) patchify -> abf1 (bf16)
  patchify_kernel<<<(Bn * NPATCH * Dn) / 256, 256, 0, stream>>>(x, abf1);
  // 2) patch embed GEMM -> (float*)abf2
  run_convT(emb_w, wtb, Dn, Dn, 1, stream);
  bgemm_kernel<0, false, 0, float><<<dim3(Dn / 128, (Bn * NPATCH + 127) / 128), 256, 0, stream>>>(
      abf1, wtb, emb_b, nullptr, (float*)abf2, Bn * NPATCH, Dn, Dn, Dn);
  // 3) assemble cls+pos -> (float*)qkvb; pre-LN -> hbuf
  assemble_kernel<<<(Bn * Sn * Dn) / 256, 256, 0, stream>>>((float*)abf2, cls, pos, (float*)qkvb);
  ln_kernel<float><<<Mrows, 256, 0, stream>>>((float*)qkvb, (size_t)Dn, pre_g, pre_b, hbuf);

  for (int l = 0; l < Ln; ++l) {
    const float* g1 = ln1_g + (size_t)l * Dn;
    const float* b1 = ln1_b + (size_t)l * Dn;
    const float* qw = qkv_w + (size_t)l * Dn * 3 * Dn;
    const float* qb = qkv_b + (size_t)l * 3 * Dn;
    const float* pw = proj_w + (size_t)l * Dn * Dn;
    const float* pb = proj_b + (size_t)l * Dn;
    const float* g2 = ln2_g + (size_t)l * Dn;
    const float* b2 = ln2_b + (size_t)l * Dn;
    const float* f1w = fc1_w + (size_t)l * Dn * DFFn;
    const float* f1b = fc1_b + (size_t)l * DFFn;
    const float* f2w = fc2_w + (size_t)l * DFFn * Dn;
    const float* f2b = fc2_b + (size_t)l * Dn;

    const bf16* wq_t = useBig ? bigq + (size_t)l * 3 * Dn * Dn : wtb;
    const bf16* wp_t = useBig ? bigp + (size_t)l * Dn * Dn     : wtb;
    const bf16* w1_t = useBig ? big1 + (size_t)l * Dn * DFFn   : wtb;
    const bf16* w2_t = useBig ? big2 + (size_t)l * DFFn * Dn   : wtb;

    // LN1: h -> y (bf16). With useSplit, layers l>0 got y from the previous
    // layer's fused redk_ln.
    if (l == 0 || !useSplit)
      ln_kernel<bf16><<<Mrows, 256, 0, stream>>>(hbuf, (size_t)Dn, g1, b1, abf1);
    // QKV: y @ qw + qb -> qkvb (bf16 [M,3D]) -- 128x256 8-wave kernel
    if (!useBig) run_convT(qw, wtb, Dn, 3 * Dn, 1, stream);
    wgemm_kernel<0, false, bf16><<<dim3(3 * Dn / 256, gM), 512, 0, stream>>>(
        abf1, wq_t, qb, nullptr, qkvb, Mrows, 3 * Dn, Dn);
    // attention (Q-split x2, KV-chunked) -> abf1 (bf16 ctx)
    attn_mfma_kernel<<<Bn * NHn * 2, 256, 0, stream>>>(qkvb, abf1);
    // proj + residual (+ fused LN2 when split): h += ctx @ pw + pb; y = LN2(h)
    if (!useBig) run_convT(pw, wtb, Dn, Dn, 1, stream);
    if (useSplit) {
      bgemm_kernel<0, false, 1, float><<<dim3(Dn / 128, gM, 2), 256, 0, stream>>>(
          abf1, wp_t, pb, nullptr, skp1, Mrows, Dn, Dn, Dn / 2);
      redk_ln_kernel<<<Mrows, 256, 0, stream>>>(skp1, skp1 + HN, pb, hbuf,
                                                g2, b2, abf1);
    } else {
      bgemm_kernel<0, true, 0, float><<<dim3(Dn / 128, gM), 256, 0, stream>>>(
          abf1, wp_t, pb, hbuf, hbuf, Mrows, Dn, Dn, Dn);
      ln_kernel<bf16><<<Mrows, 256, 0, stream>>>(hbuf, (size_t)Dn, g2, b2, abf1);
    }
    // fc1 + gelu -> abf2 (bf16 [M,DFF]) -- 128x256 8-wave kernel
    if (!useBig) run_convT(f1w, wtb, Dn, DFFn, 1, stream);
    wgemm_kernel<1, false, bf16><<<dim3(DFFn / 256, gM), 512, 0, stream>>>(
        abf1, w1_t, f1b, nullptr, abf2, Mrows, DFFn, Dn);
    // fc2 + residual: h += m @ f2w + f2b
    if (!useBig) run_convT(f2w, wtb, DFFn, Dn, 1, stream);
    if (useSplit) {
      bgemm_kernel<0, false, 1, float><<<dim3(Dn / 128, gM, 2), 256, 0, stream>>>(
          abf2, w2_t, f2b, nullptr, skp1, Mrows, Dn, DFFn, DFFn / 2);
      if (l + 1 < Ln) {
        const float* g1n = ln1_g + (size_t)(l + 1) * Dn;
        const float* b1n = ln1_b + (size_t)(l + 1) * Dn;
        redk_ln_kernel<<<Mrows, 256, 0, stream>>>(skp1, skp1 + HN, f2b, hbuf,
                                                  g1n, b1n, abf1);
      } else {
        redk_kernel<<<(Mrows * Dn / 4 + 255) / 256, 256, 0, stream>>>(
            skp1, skp1 + HN, f2b, hbuf, Mrows * Dn / 4);
      }
    } else {
      bgemm_kernel<0, true, 0, float><<<dim3(Dn / 128, gM), 256, 0, stream>>>(
          abf2, w2_t, f2b, hbuf, hbuf, Mrows, Dn, DFFn, DFFn);
    }
  }

  // head: post-LN of h[:,0,:] -> t1; tanh GEMV -> t2; logits GEMV -> out
  float* t1 = (float*)abf2;
  float* t2 = t1 + Bn * Dn;
  ln_kernel<float><<<Bn, 256, 0, stream>>>(hbuf, (size_t)Sn * Dn, post_g, post_b, t1);
  run_convT(h1_w, wtb, Dn, Dn, 1, stream);
  hgemv_kernel<2><<<Bn * Dn / 4, 256, 0, stream>>>(t1, wtb, h1_b, t2, Dn, Dn);
  run_convT(h2_w, wtb, Dn, OUTn, 1, stream);
  hgemv_kernel<0><<<Bn * OUTn / 4, 256, 0, stream>>>(t2, wtb, h2_b, out, OUTn, Dn);
}

// Round 19
// 2695.310 us; speedup vs baseline: 1.0084x; 1.0084x over previous
//
#include <hip/hip_runtime.h>
#include <hip/hip_bf16.h>
#include <math.h>
#include <cstdint>

// ---------------- problem constants ----------------
constexpr int Bn   = 32;
constexpr int Dn   = 768;
constexpr int NHn  = 12;
constexpr int HDn  = 64;
constexpr int Ln   = 12;
constexpr int DFFn = 3072;
constexpr int OUTn = 1000;
constexpr int Sn   = 197;          // 14*14 + 1 tokens
constexpr int Mrows = Bn * Sn;     // 6304
constexpr int NPATCH = 196;

typedef __attribute__((ext_vector_type(8))) short bf16x8;
typedef __attribute__((ext_vector_type(4))) float f32x4;

__device__ inline void store_val(float* p, float v) { *p = v; }
__device__ inline void store_val(__hip_bfloat16* p, float v) { *p = __float2bfloat16(v); }
__device__ inline short f2bs(float f) {
  __hip_bfloat16 h = __float2bfloat16(f);
  return __builtin_bit_cast(short, h);
}

// async global->LDS, 16B per lane; LDS dest = wave-uniform base + lane*16
__device__ inline void gload_lds16(const void* g, void* l) {
  auto gp = (const __attribute__((address_space(1))) unsigned int*)(uintptr_t)g;
  auto lp = (__attribute__((address_space(3))) unsigned int*)(uintptr_t)l;
  __builtin_amdgcn_global_load_lds(gp, lp, 16, 0, 0);
}

// bijective XCD-chunk swizzle (m204)
__device__ inline int xcd_swizzle(int orig, int nwg) {
  const int xcd = orig & 7, local = orig >> 3;
  const int q = nwg >> 3, r = nwg & 7;
  return (xcd < r) ? xcd * (q + 1) + local : r * (q + 1) + (xcd - r) * q + local;
}

// ---------------- bf16 MFMA GEMM: 128x128, 3-buffer ring, counted vmcnt ----------------
template<int ACT, bool RES, int SPLITK, typename OT>   // ACT: 0 none, 1 gelu
__global__ __launch_bounds__(256) void bgemm_kernel(
    const __hip_bfloat16* __restrict__ A,
    const __hip_bfloat16* __restrict__ Bt,
    const float* __restrict__ bias,
    const float* __restrict__ res,
    OT* __restrict__ out, int M, int N, int K, int kloop)
{
  __shared__ __hip_bfloat16 As[3][128 * 32];   // 3 x 8 KB
  __shared__ __hip_bfloat16 Bs[3][128 * 32];
  const int tid  = threadIdx.x;
  const int w    = tid >> 6, lane = tid & 63;
  const int wm   = w >> 1,   wn   = w & 1;
  const int kg   = lane >> 4, fr = lane & 15;

  if (SPLITK) {
    const int koff = blockIdx.z * kloop;
    A  += koff;
    Bt += koff;
    out += (size_t)blockIdx.z * M * N;
  }

  const int nwg = gridDim.x * gridDim.y;
  const int wg  = xcd_swizzle(blockIdx.y * gridDim.x + blockIdx.x, nwg);
  const int bm  = (wg / gridDim.x) * 128;
  const int bn  = (wg % gridDim.x) * 128;

  const int obase0 = w * 2048;
  const int obase1 = w * 2048 + 1024;
  const int o0 = obase0 + lane * 16, o1 = obase1 + lane * 16;
  const int r0 = o0 >> 6,            r1 = o1 >> 6;
  const int ks0 = (((o0 >> 4) & 3) ^ ((r0 >> 1) & 3)) * 8;
  const int ks1 = (((o1 >> 4) & 3) ^ ((r1 >> 1) & 3)) * 8;
  const int ga0 = (bm + r0 >= M) ? M - 1 : bm + r0;
  const int ga1 = (bm + r1 >= M) ? M - 1 : bm + r1;
  const int gb0 = bn + r0, gb1 = bn + r1;

  f32x4 acc[4][4];
  #pragma unroll
  for (int i = 0; i < 4; ++i)
    #pragma unroll
    for (int j = 0; j < 4; ++j) acc[i][j] = (f32x4)(0.f);

  const int nt = kloop >> 5;

  auto STAGE = [&](int t, int bi) {
    const int k0 = t << 5;
    gload_lds16(A  + (size_t)ga0 * K + k0 + ks0, (char*)As[bi] + obase0);
    gload_lds16(A  + (size_t)ga1 * K + k0 + ks1, (char*)As[bi] + obase1);
    gload_lds16(Bt + (size_t)gb0 * K + k0 + ks0, (char*)Bs[bi] + obase0);
    gload_lds16(Bt + (size_t)gb1 * K + k0 + ks1, (char*)Bs[bi] + obase1);
  };
  auto COMPUTE = [&](int bi) {
    bf16x8 af[4], bfv[4];
    #pragma unroll
    for (int tt = 0; tt < 4; ++tt) {
      const int r = wm * 64 + tt * 16 + fr;
      af[tt]  = *(const bf16x8*)((const char*)As[bi] + r * 64 + ((kg ^ ((r >> 1) & 3)) << 4));
      const int c = wn * 64 + tt * 16 + fr;
      bfv[tt] = *(const bf16x8*)((const char*)Bs[bi] + c * 64 + ((kg ^ ((c >> 1) & 3)) << 4));
    }
    #pragma unroll
    for (int mt = 0; mt < 4; ++mt)
      #pragma unroll
      for (int nt2 = 0; nt2 < 4; ++nt2)
        acc[mt][nt2] = __builtin_amdgcn_mfma_f32_16x16x32_bf16(af[mt], bfv[nt2], acc[mt][nt2], 0, 0, 0);
  };

  STAGE(0, 0);
  STAGE(1, 1);

  int cur = 0;
  for (int t = 0; t < nt - 1; ++t) {
    asm volatile("s_waitcnt vmcnt(4)" ::: "memory");
    __builtin_amdgcn_s_barrier();
    __builtin_amdgcn_sched_barrier(0);
    if (t + 2 < nt) {
      int nb = cur + 2; if (nb >= 3) nb -= 3;
      STAGE(t + 2, nb);
    }
    COMPUTE(cur);
    ++cur; if (cur == 3) cur = 0;
  }
  asm volatile("s_waitcnt vmcnt(0)" ::: "memory");
  __builtin_amdgcn_s_barrier();
  __builtin_amdgcn_sched_barrier(0);
  COMPUTE(cur);

  #pragma unroll
  for (int nt2 = 0; nt2 < 4; ++nt2) {
    const int cb = bn + wn * 64 + nt2 * 16 + fr;
    const float bs = SPLITK ? 0.f : bias[cb];
    #pragma unroll
    for (int mt = 0; mt < 4; ++mt) {
      #pragma unroll
      for (int j = 0; j < 4; ++j) {
        const int rb = bm + wm * 64 + mt * 16 + kg * 4 + j;
        if (rb >= M) continue;
        float v = acc[mt][nt2][j] + bs;
        if (ACT == 1) v = 0.5f * v * (1.f + erff(v * 0.70710678118654752f));
        if (RES) v += res[(size_t)rb * N + cb];
        store_val(out + (size_t)rb * N + cb, v);
      }
    }
  }
}

// ---------------- split-K reduce: h += p0 + p1 + bias (elementwise) ----------------
__global__ __launch_bounds__(256) void redk_kernel(const float* __restrict__ p0,
                                                   const float* __restrict__ p1,
                                                   const float* __restrict__ bias,
                                                   float* __restrict__ h, int n4)
{
  const int i = blockIdx.x * 256 + threadIdx.x;
  if (i >= n4) return;
  const float4 a = ((const float4*)p0)[i];
  const float4 b = ((const float4*)p1)[i];
  const float4 r = ((const float4*)h)[i];
  const float4 bs = ((const float4*)bias)[i % (Dn / 4)];
  float4 o;
  o.x = r.x + a.x + b.x + bs.x;
  o.y = r.y + a.y + b.y + bs.y;
  o.z = r.z + a.z + b.z + bs.z;
  o.w = r.w + a.w + b.w + bs.w;
  ((float4*)h)[i] = o;
}

// ---------------- fused split-K reduce + LayerNorm ----------------
__global__ __launch_bounds__(256) void redk_ln_kernel(
    const float* __restrict__ p0, const float* __restrict__ p1,
    const float* __restrict__ bias, float* __restrict__ h,
    const float* __restrict__ g, const float* __restrict__ bt,
    __hip_bfloat16* __restrict__ y)
{
  const int row = blockIdx.x;
  const int tid = threadIdx.x;
  const size_t base = (size_t)row * Dn;
  float hv[3];
  #pragma unroll
  for (int i = 0; i < 3; ++i) {
    const int c = tid + i * 256;
    const size_t idx = base + c;
    hv[i] = h[idx] + p0[idx] + p1[idx] + bias[c];
    h[idx] = hv[i];
  }
  float s = hv[0] + hv[1] + hv[2];
  float q = hv[0] * hv[0] + hv[1] * hv[1] + hv[2] * hv[2];
  #pragma unroll
  for (int o = 32; o > 0; o >>= 1) { s += __shfl_down(s, o); q += __shfl_down(q, o); }
  __shared__ float sa[4], sb[4];
  const int w = tid >> 6, lane = tid & 63;
  if (lane == 0) { sa[w] = s; sb[w] = q; }
  __syncthreads();
  if (tid == 0) {
    sa[0] = sa[0] + sa[1] + sa[2] + sa[3];
    sb[0] = sb[0] + sb[1] + sb[2] + sb[3];
  }
  __syncthreads();
  s = sa[0]; q = sb[0];
  const float mean = s * (1.f / 768.f);
  const float var  = q * (1.f / 768.f) - mean * mean;
  const float inv  = rsqrtf(var + 1e-5f);
  __hip_bfloat16* yr = y + base;
  #pragma unroll
  for (int i = 0; i < 3; ++i) {
    const int c = tid + i * 256;
    yr[c] = __float2bfloat16((hv[i] - mean) * inv * g[c] + bt[c]);
  }
}

// ---------------- bf16 MFMA GEMM: 128x256, 8 waves, 3-ring, counted vmcnt ----------------
template<int ACT, bool RES, typename OT>
__global__ __launch_bounds__(512) void wgemm_kernel(
    const __hip_bfloat16* __restrict__ A,
    const __hip_bfloat16* __restrict__ Bt,
    const float* __restrict__ bias,
    const float* __restrict__ res,
    OT* __restrict__ out, int M, int N, int K)
{
  constexpr int BUFSZ = 24576;
  __shared__ __align__(16) char lds[3 * BUFSZ];   // 72 KB
  const int tid  = threadIdx.x;
  const int wid  = tid >> 6, lane = tid & 63;
  const int wm   = wid >> 2, wn = wid & 3;        // 2M x 4N waves
  const int kg   = lane >> 4, fr = lane & 15;
  const int rs   = lane >> 2;                     // row within 16-row chunk
  const int ks   = (((lane & 3) ^ ((lane >> 3) & 3)) << 3);  // pre-swizzled k-elems

  const int gx  = gridDim.x;
  const int nwg = gx * gridDim.y;
  const int wg  = xcd_swizzle(blockIdx.y * gx + blockIdx.x, nwg);
  const int bm  = (wg / gx) * 128;
  const int bn  = (wg % gx) * 256;

  f32x4 acc[4][4];
  #pragma unroll
  for (int i = 0; i < 4; ++i)
    #pragma unroll
    for (int j = 0; j < 4; ++j) acc[i][j] = (f32x4)(0.f);

  const int nt = K >> 5;

  auto STAGE = [&](int t) {
    const int k0 = t << 5;
    char* buf = lds + (t % 3) * BUFSZ;
    #pragma unroll
    for (int j = 0; j < 3; ++j) {
      const int c = wid + j * 8;                  // 0..23
      const __hip_bfloat16* src;
      if (c < 8) {                                // A chunk: tile rows c*16..+15
        int gr = bm + c * 16 + rs; if (gr >= M) gr = M - 1;
        src = A + (size_t)gr * K + k0 + ks;
      } else {                                    // B chunk: tile cols (c-8)*16..+15
        const int gc = bn + (c - 8) * 16 + rs;    // N multiple of 256 here
        src = Bt + (size_t)gc * K + k0 + ks;
      }
      gload_lds16(src, buf + c * 1024);           // wave-uniform base + lane*16
    }
  };
  auto COMPUTE = [&](int t) {
    const char* buf = lds + (t % 3) * BUFSZ;
    bf16x8 af[4], bfv[4];
    #pragma unroll
    for (int tt = 0; tt < 4; ++tt) {
      const int r = wm * 64 + tt * 16 + fr;       // 0..127
      af[tt]  = *(const bf16x8*)(buf + r * 64 + ((kg ^ ((r >> 1) & 3)) << 4));
      const int c = wn * 64 + tt * 16 + fr;       // 0..255
      bfv[tt] = *(const bf16x8*)(buf + 8192 + c * 64 + ((kg ^ ((c >> 1) & 3)) << 4));
    }
    #pragma unroll
    for (int mt = 0; mt < 4; ++mt)
      #pragma unroll
      for (int nt2 = 0; nt2 < 4; ++nt2)
        acc[mt][nt2] = __builtin_amdgcn_mfma_f32_16x16x32_bf16(af[mt], bfv[nt2], acc[mt][nt2], 0, 0, 0);
  };

  STAGE(0);
  STAGE(1);

  for (int t = 0; t < nt - 1; ++t) {
    asm volatile("s_waitcnt vmcnt(3)" ::: "memory");
    __builtin_amdgcn_s_barrier();
    __builtin_amdgcn_sched_barrier(0);
    if (t + 2 < nt) STAGE(t + 2);
    COMPUTE(t);
  }
  asm volatile("s_waitcnt vmcnt(0)" ::: "memory");
  __builtin_amdgcn_s_barrier();
  __builtin_amdgcn_sched_barrier(0);
  COMPUTE(nt - 1);

  if constexpr (sizeof(OT) == 2) {
    // bf16 output: repack through LDS so global stores are full-line 16B/lane.
    __syncthreads();
    short* ct = (short*)lds;                      // [128][256]
    #pragma unroll
    for (int fj = 0; fj < 4; ++fj) {
      const int col = wn * 64 + fj * 16 + fr;
      const float bs = bias[bn + col];
      #pragma unroll
      for (int fi = 0; fi < 4; ++fi)
        #pragma unroll
        for (int j = 0; j < 4; ++j) {
          const int row = wm * 64 + fi * 16 + kg * 4 + j;
          float v = acc[fi][fj][j] + bs;
          if (ACT == 1) v = 0.5f * v * (1.f + erff(v * 0.70710678118654752f));
          ct[row * 256 + col] = f2bs(v);
        }
    }
    __syncthreads();
    #pragma unroll
    for (int c = 0; c < 8; ++c) {
      const int chunk = tid + c * 512;            // 0..4095
      const int row = chunk >> 5, ce = (chunk & 31) * 8;
      const int grow = bm + row;
      if (grow < M)
        *(bf16x8*)((short*)out + (size_t)grow * N + bn + ce) =
            *(const bf16x8*)(ct + row * 256 + ce);
    }
  } else {
    #pragma unroll
    for (int fj = 0; fj < 4; ++fj) {
      const int col = bn + wn * 64 + fj * 16 + fr;
      const float bs = bias[col];
      #pragma unroll
      for (int fi = 0; fi < 4; ++fi) {
        #pragma unroll
        for (int j = 0; j < 4; ++j) {
          const int row = bm + wm * 64 + fi * 16 + kg * 4 + j;
          if (row >= M) continue;
          float v = acc[fi][fj][j] + bs;
          if (ACT == 1) v = 0.5f * v * (1.f + erff(v * 0.70710678118654752f));
          if (RES) v += res[(size_t)row * N + col];
          store_val(out + (size_t)row * N + col, v);
        }
      }
    }
  }
}

// ---------------- transpose-convert: W[z][K,N] fp32 -> Wt[z][N,K] bf16 (guarded) ----------------
__global__ __launch_bounds__(256) void convT_kernel(const float* __restrict__ W,
                                                    __hip_bfloat16* __restrict__ Wt,
                                                    int K, int N)
{
  const size_t lw = (size_t)K * N;
  const float* Wb = W + blockIdx.z * lw;
  __hip_bfloat16* Wo = Wt + blockIdx.z * lw;
  __shared__ float t[32][33];
  const int k0 = blockIdx.y * 32, n0 = blockIdx.x * 32;
  const int r  = threadIdx.x >> 3, c4 = (threadIdx.x & 7) * 4;
  const float* wp = Wb + (size_t)(k0 + r) * N + n0 + c4;
  float4 v = make_float4(0.f, 0.f, 0.f, 0.f);
  if (n0 + c4 + 3 < N) v = *(const float4*)wp;
  else {
    if (n0 + c4 + 0 < N) v.x = wp[0];
    if (n0 + c4 + 1 < N) v.y = wp[1];
    if (n0 + c4 + 2 < N) v.z = wp[2];
  }
  t[r][c4 + 0] = v.x; t[r][c4 + 1] = v.y; t[r][c4 + 2] = v.z; t[r][c4 + 3] = v.w;
  __syncthreads();
  const int n = n0 + r;
  if (n < N) {
    __hip_bfloat16* o = Wo + (size_t)n * K + k0 + c4;
    o[0] = __float2bfloat16(t[c4 + 0][r]);
    o[1] = __float2bfloat16(t[c4 + 1][r]);
    o[2] = __float2bfloat16(t[c4 + 2][r]);
    o[3] = __float2bfloat16(t[c4 + 3][r]);
  }
}

// ---------------- head GEMV: out[32,N] = act(A[32,K] @ Wt[N,K]^T + bias) ----------------
template<int ACT>   // 0 none, 2 tanh
__global__ __launch_bounds__(256) void hgemv_kernel(
    const float* __restrict__ A, const __hip_bfloat16* __restrict__ Wt,
    const float* __restrict__ bias, float* __restrict__ out, int N, int K)
{
  const int w = threadIdx.x >> 6, lane = threadIdx.x & 63;
  const int e = blockIdx.x * 4 + w;
  const int m = e & 31, n = e >> 5;
  if (n >= N) return;
  const float* a = A + (size_t)m * K;
  const __hip_bfloat16* wr = Wt + (size_t)n * K;
  float s = 0.f;
  for (int k = lane; k < K; k += 64)
    s = fmaf(a[k], __bfloat162float(wr[k]), s);
  #pragma unroll
  for (int o = 32; o > 0; o >>= 1) s += __shfl_xor(s, o);
  if (lane == 0) {
    float v = s + bias[n];
    if (ACT == 2) v = tanhf(v);
    out[(size_t)m * N + n] = v;
  }
}

// ---------------- patchify: x[B,C,224,224] -> patches[B*196, 768] bf16 ----------------
__global__ __launch_bounds__(256) void patchify_kernel(const float* __restrict__ x,
                                                       __hip_bfloat16* __restrict__ p)
{
  size_t i = (size_t)blockIdx.x * 256 + threadIdx.x;
  constexpr size_t total = (size_t)Bn * NPATCH * 768;
  if (i >= total) return;
  int k = (int)(i % 768);
  size_t m = i / 768;
  int b = (int)(m / NPATCH), pp = (int)(m % NPATCH);
  int py = pp / 14, px = pp % 14;
  int c = k >> 8, ph = (k >> 4) & 15, pw = k & 15;
  p[i] = __float2bfloat16(x[(((size_t)(b * 3 + c)) * 224 + py * 16 + ph) * 224 + px * 16 + pw]);
}

// ---------------- assemble: tokens+cls+pos -> [B,S,D] fp32 ----------------
__global__ __launch_bounds__(256) void assemble_kernel(const float* __restrict__ tok,
                                                       const float* __restrict__ cls,
                                                       const float* __restrict__ pos,
                                                       float* __restrict__ outp)
{
  size_t i = (size_t)blockIdx.x * 256 + threadIdx.x;
  constexpr size_t total = (size_t)Bn * Sn * Dn;
  if (i >= total) return;
  int d = (int)(i % Dn);
  size_t m = i / Dn;
  int s = (int)(m % Sn);
  size_t b = m / Sn;
  float v = (s == 0) ? cls[d] : tok[(b * NPATCH + (s - 1)) * Dn + d];
  outp[i] = v + pos[s * Dn + d];
}

// ---------------- LayerNorm over D=768, one block per row ----------------
template<typename OT>
__global__ __launch_bounds__(256) void ln_kernel(const float* __restrict__ x, size_t xstride,
                                                 const float* __restrict__ g,
                                                 const float* __restrict__ bt,
                                                 OT* __restrict__ out)
{
  const int row = blockIdx.x;
  const int tid = threadIdx.x;
  const float* xr = x + (size_t)row * xstride;
  float v0 = xr[tid], v1 = xr[tid + 256], v2 = xr[tid + 512];
  float s = v0 + v1 + v2;
  float q = v0 * v0 + v1 * v1 + v2 * v2;
  #pragma unroll
  for (int o = 32; o > 0; o >>= 1) { s += __shfl_down(s, o); q += __shfl_down(q, o); }
  __shared__ float sa[4], sb[4];
  int w = tid >> 6, lane = tid & 63;
  if (lane == 0) { sa[w] = s; sb[w] = q; }
  __syncthreads();
  if (tid == 0) {
    float ts = sa[0] + sa[1] + sa[2] + sa[3];
    float tq = sb[0] + sb[1] + sb[2] + sb[3];
    sa[0] = ts; sb[0] = tq;
  }
  __syncthreads();
  s = sa[0]; q = sb[0];
  const float mean = s * (1.f / 768.f);
  const float var  = q * (1.f / 768.f) - mean * mean;
  const float inv  = rsqrtf(var + 1e-5f);
  OT* orow = out + (size_t)row * Dn;
  store_val(orow + tid,       (v0 - mean) * inv * g[tid]       + bt[tid]);
  store_val(orow + tid + 256, (v1 - mean) * inv * g[tid + 256] + bt[tid + 256]);
  store_val(orow + tid + 512, (v2 - mean) * inv * g[tid + 512] + bt[tid + 512]);
}

// ---------------- MFMA flash attention (Q-split: 2 blocks per head) ----------------
constexpr int SP2 = 224;
constexpr int VTS = 232;
__global__ __launch_bounds__(256) void attn_mfma_kernel(
    const __hip_bfloat16* __restrict__ qkv, __hip_bfloat16* __restrict__ ctx)
{
  const int bh = blockIdx.x >> 1, qh = blockIdx.x & 1;
  const int b = bh / NHn, h = bh % NHn;
  const int tid = threadIdx.x;
  const int w = tid >> 6, lane = tid & 63;
  const int kg = lane >> 4, fr = lane & 15;

  __shared__ short Kl[SP2 * 64];       // 28672 B
  __shared__ short Vt[64 * VTS];       // 29696 B
  __shared__ short Pl[4 * 2048];       // 16384 B, per-wave tile

  const size_t rstr = 3 * (size_t)Dn;  // 2304
  const __hip_bfloat16* base = qkv + (size_t)b * Sn * rstr;

  #pragma unroll
  for (int it = 0; it < 7; ++it) {
    const int i = it * 256 + tid;
    const int r = i >> 3, s = i & 7;
    const int rr = r < Sn ? r : Sn - 1;
    gload_lds16(base + (size_t)rr * rstr + Dn + h * HDn + ((s ^ (r & 7)) << 3),
                (char*)Kl + it * 4096 + w * 1024);
  }
  #pragma unroll
  for (int it = 0; it < 7; ++it) {
    const int i = it * 256 + tid;
    const int key = i >> 3, d0 = (i & 7) * 8;
    const int rr = key < Sn ? key : Sn - 1;
    bf16x8 v = *(const bf16x8*)(base + (size_t)rr * rstr + 2 * Dn + h * HDn + d0);
    #pragma unroll
    for (int e = 0; e < 8; ++e) Vt[(d0 + e) * VTS + key] = v[e];
  }
  // this block's 128 Q rows: qh*128 + w*32 .. +31
  const int qw = qh * 128 + w * 32;
  bf16x8 qf[2][2];
  #pragma unroll
  for (int qt = 0; qt < 2; ++qt)
    #pragma unroll
    for (int kk = 0; kk < 2; ++kk) {
      int q = qw + qt * 16 + fr; if (q >= Sn) q = Sn - 1;
      qf[qt][kk] = *(const bf16x8*)(base + (size_t)q * rstr + h * HDn + kk * 32 + kg * 8);
    }
  __syncthreads();

  float mold[2][4], lsum[2][4];
  f32x4 cacc[2][4];
  #pragma unroll
  for (int qt = 0; qt < 2; ++qt)
    #pragma unroll
    for (int j = 0; j < 4; ++j) {
      mold[qt][j] = -1e30f; lsum[qt][j] = 0.f;
      cacc[qt][j] = (f32x4)(0.f);
    }
  const float scale = 0.125f;

  for (int kc = 0; kc < SP2; kc += 32) {
    f32x4 sacc[2][2];
    #pragma unroll
    for (int qt = 0; qt < 2; ++qt) { sacc[qt][0] = (f32x4)(0.f); sacc[qt][1] = (f32x4)(0.f); }
    #pragma unroll
    for (int nt = 0; nt < 2; ++nt) {
      const int key = kc + nt * 16 + fr;
      const bf16x8 kf0 = *(const bf16x8*)((const char*)Kl + key * 128 + ((kg ^ (key & 7)) << 4));
      const bf16x8 kf1 = *(const bf16x8*)((const char*)Kl + key * 128 + (((4 + kg) ^ (key & 7)) << 4));
      #pragma unroll
      for (int qt = 0; qt < 2; ++qt) {
        sacc[qt][nt] = __builtin_amdgcn_mfma_f32_16x16x32_bf16(qf[qt][0], kf0, sacc[qt][nt], 0, 0, 0);
        sacc[qt][nt] = __builtin_amdgcn_mfma_f32_16x16x32_bf16(qf[qt][1], kf1, sacc[qt][nt], 0, 0, 0);
      }
    }
    const float madd0 = (kc + fr < Sn) ? 0.f : -3e38f;
    const float madd1 = (kc + 16 + fr < Sn) ? 0.f : -3e38f;
    #pragma unroll
    for (int qt = 0; qt < 2; ++qt) {
      sacc[qt][0] = sacc[qt][0] * scale + (f32x4)(madd0);
      sacc[qt][1] = sacc[qt][1] * scale + (f32x4)(madd1);
    }
    #pragma unroll
    for (int qt = 0; qt < 2; ++qt) {
      #pragma unroll
      for (int j = 0; j < 4; ++j) {
        float t = fmaxf(sacc[qt][0][j], sacc[qt][1][j]);
        t = fmaxf(t, __shfl_xor(t, 1));
        t = fmaxf(t, __shfl_xor(t, 2));
        t = fmaxf(t, __shfl_xor(t, 4));
        t = fmaxf(t, __shfl_xor(t, 8));
        const float mn = fmaxf(mold[qt][j], t);
        const float corr = __expf(mold[qt][j] - mn);
        mold[qt][j] = mn;
        const float p0 = __expf(sacc[qt][0][j] - mn);
        const float p1 = __expf(sacc[qt][1][j] - mn);
        sacc[qt][0][j] = p0; sacc[qt][1][j] = p1;
        float ps = p0 + p1;
        ps += __shfl_xor(ps, 1); ps += __shfl_xor(ps, 2);
        ps += __shfl_xor(ps, 4); ps += __shfl_xor(ps, 8);
        lsum[qt][j] = lsum[qt][j] * corr + ps;
        #pragma unroll
        for (int ht = 0; ht < 4; ++ht) cacc[qt][ht][j] *= corr;
      }
      #pragma unroll
      for (int nt = 0; nt < 2; ++nt) {
        const int c = nt * 16 + fr;
        #pragma unroll
        for (int j = 0; j < 4; ++j) {
          const int r = qt * 16 + kg * 4 + j;
          Pl[w * 2048 + r * 32 + (((c >> 3) ^ (r & 3)) << 3) + (c & 7)] = f2bs(sacc[qt][nt][j]);
        }
      }
    }
    bf16x8 vf[4];
    #pragma unroll
    for (int ht = 0; ht < 4; ++ht)
      vf[ht] = *(const bf16x8*)(Vt + (ht * 16 + fr) * VTS + kc + kg * 8);
    #pragma unroll
    for (int qt = 0; qt < 2; ++qt) {
      const int r = qt * 16 + fr;
      const bf16x8 pf = *(const bf16x8*)(Pl + w * 2048 + r * 32 + ((kg ^ (r & 3)) << 3));
      #pragma unroll
      for (int ht = 0; ht < 4; ++ht)
        cacc[qt][ht] = __builtin_amdgcn_mfma_f32_16x16x32_bf16(pf, vf[ht], cacc[qt][ht], 0, 0, 0);
    }
  }
  __hip_bfloat16* cb = ctx + (size_t)b * Sn * Dn + h * HDn;
  #pragma unroll
  for (int qt = 0; qt < 2; ++qt)
    #pragma unroll
    for (int j = 0; j < 4; ++j) {
      const int q = qw + qt * 16 + kg * 4 + j;
      if (q < Sn) {
        const float inv = 1.f / lsum[qt][j];
        #pragma unroll
        for (int ht = 0; ht < 4; ++ht)
          cb[(size_t)q * Dn + ht * 16 + fr] = __float2bfloat16(cacc[qt][ht][j] * inv);
      }
    }
}

// ---------------- host side ----------------
using bf16 = __hip_bfloat16;

static inline void run_convT(const float* W, bf16* Wt, int K, int N, int L, hipStream_t st) {
  convT_kernel<<<dim3((N + 31) / 32, K / 32, L), 256, 0, st>>>(W, Wt, K, N);
}

extern "C" void kernel_launch(void* const* d_in, const int* in_sizes, int n_in,
                              void* d_out, int out_size, void* d_ws, size_t ws_size,
                              hipStream_t stream)
{
  const float* x      = (const float*)d_in[0];
  const float* emb_w  = (const float*)d_in[1];
  const float* emb_b  = (const float*)d_in[2];
  const float* cls    = (const float*)d_in[3];
  const float* pos    = (const float*)d_in[4];
  const float* pre_g  = (const float*)d_in[5];
  const float* pre_b  = (const float*)d_in[6];
  const float* ln1_g  = (const float*)d_in[7];
  const float* ln1_b  = (const float*)d_in[8];
  const float* qkv_w  = (const float*)d_in[9];
  const float* qkv_b  = (const float*)d_in[10];
  const float* proj_w = (const float*)d_in[11];
  const float* proj_b = (const float*)d_in[12];
  const float* ln2_g  = (const float*)d_in[13];
  const float* ln2_b  = (const float*)d_in[14];
  const float* fc1_w  = (const float*)d_in[15];
  const float* fc1_b  = (const float*)d_in[16];
  const float* fc2_w  = (const float*)d_in[17];
  const float* fc2_b  = (const float*)d_in[18];
  const float* post_g = (const float*)d_in[19];
  const float* post_b = (const float*)d_in[20];
  const float* h1_w   = (const float*)d_in[21];
  const float* h1_b   = (const float*)d_in[22];
  const float* h2_w   = (const float*)d_in[23];
  const float* h2_b   = (const float*)d_in[24];
  float* out = (float*)d_out;

  // workspace layout
  const size_t HN = (size_t)Mrows * Dn;
  float* hbuf = (float*)d_ws;                         // fp32 residual [M,768]
  bf16*  qkvb = (bf16*)(hbuf + HN);                   // bf16 [M,2304]; also fp32 staging
  bf16*  abf1 = qkvb + (size_t)Mrows * 3 * Dn;        // bf16 [M,768]
  bf16*  abf2 = abf1 + HN;                            // bf16 [M,3072]; also fp32 staging
  bf16*  wtb  = abf2 + (size_t)Mrows * DFFn;          // bf16 scratch Wt (max 2304x768)

  // optional pre-converted all-layer weights (bf16, transposed)
  bf16* bigq = wtb + (size_t)2304 * 768;
  bf16* bigp = bigq + (size_t)Ln * 3 * Dn * Dn;
  bf16* big1 = bigp + (size_t)Ln * Dn * Dn;
  bf16* big2 = big1 + (size_t)Ln * Dn * DFFn;
  bf16* endBig = big2 + (size_t)Ln * DFFn * Dn;
  const size_t need_big = (size_t)((char*)endBig - (char*)d_ws);
  const bool useBig = ws_size >= need_big;

  // split-K partials: two contiguous fp32 planes of HN at endBig.
  float* skp1 = (float*)endBig;
  const size_t need_split = need_big + 2 * HN * sizeof(float);
  const bool useSplit = useBig && ws_size >= need_split;

  const int gM = (Mrows + 127) / 128;                 // 50

  if (useBig) {
    run_convT(qkv_w,  bigq, Dn, 3 * Dn, Ln, stream);
    run_convT(proj_w, bigp, Dn, Dn,     Ln, stream);
    run_convT(fc1_w,  big1, Dn, DFFn,   Ln, stream);
    run_convT(fc2_w,  big2, DFFn, Dn,   Ln, stream);
  }

  // 1) patchify -> abf1 (bf16)
  patchify_kernel<<<(Bn * NPATCH * Dn) / 256, 256, 0, stream>>>(x, abf1);
  // 2) patch embed GEMM -> (float*)abf2
  run_convT(emb_w, wtb, Dn, Dn, 1, stream);
  bgemm_kernel<0, false, 0, float><<<dim3(Dn / 128, (Bn * NPATCH + 127) / 128), 256, 0, stream>>>(
      abf1, wtb, emb_b, nullptr, (float*)abf2, Bn * NPATCH, Dn, Dn, Dn);
  // 3) assemble cls+pos -> (float*)qkvb; pre-LN -> hbuf
  assemble_kernel<<<(Bn * Sn * Dn) / 256, 256, 0, stream>>>((float*)abf2, cls, pos, (float*)qkvb);
  ln_kernel<float><<<Mrows, 256, 0, stream>>>((float*)qkvb, (size_t)Dn, pre_g, pre_b, hbuf);

  for (int l = 0; l < Ln; ++l) {
    const float* g1 = ln1_g + (size_t)l * Dn;
    const float* b1 = ln1_b + (size_t)l * Dn;
    const float* qw = qkv_w + (size_t)l * Dn * 3 * Dn;
    const float* qb = qkv_b + (size_t)l * 3 * Dn;
    const float* pw = proj_w + (size_t)l * Dn * Dn;
    const float* pb = proj_b + (size_t)l * Dn;
    const float* g2 = ln2_g + (size_t)l * Dn;
    const float* b2 = ln2_b + (size_t)l * Dn;
    const float* f1w = fc1_w + (size_t)l * Dn * DFFn;
    const float* f1b = fc1_b + (size_t)l * DFFn;
    const float* f2w = fc2_w + (size_t)l * DFFn * Dn;
    const float* f2b = fc2_b + (size_t)l * Dn;

    const bf16* wq_t = useBig ? bigq + (size_t)l * 3 * Dn * Dn : wtb;
    const bf16* wp_t = useBig ? bigp + (size_t)l * Dn * Dn     : wtb;
    const bf16* w1_t = useBig ? big1 + (size_t)l * Dn * DFFn   : wtb;
    const bf16* w2_t = useBig ? big2 + (size_t)l * DFFn * Dn   : wtb;

    // LN1: h -> y (bf16). With useSplit, layers l>0 got y from the previous
    // layer's fused redk_ln.
    if (l == 0 || !useSplit)
      ln_kernel<bf16><<<Mrows, 256, 0, stream>>>(hbuf, (size_t)Dn, g1, b1, abf1);
    // QKV: y @ qw + qb -> qkvb (bf16 [M,3D]) -- 128x256 8-wave kernel
    if (!useBig) run_convT(qw, wtb, Dn, 3 * Dn, 1, stream);
    wgemm_kernel<0, false, bf16><<<dim3(3 * Dn / 256, gM), 512, 0, stream>>>(
        abf1, wq_t, qb, nullptr, qkvb, Mrows, 3 * Dn, Dn);
    // attention (Q-split x2) -> abf1 (bf16 ctx)
    attn_mfma_kernel<<<Bn * NHn * 2, 256, 0, stream>>>(qkvb, abf1);
    // proj + residual (+ fused LN2 when split): h += ctx @ pw + pb; y = LN2(h)
    if (!useBig) run_convT(pw, wtb, Dn, Dn, 1, stream);
    if (useSplit) {
      bgemm_kernel<0, false, 1, float><<<dim3(Dn / 128, gM, 2), 256, 0, stream>>>(
          abf1, wp_t, pb, nullptr, skp1, Mrows, Dn, Dn, Dn / 2);
      redk_ln_kernel<<<Mrows, 256, 0, stream>>>(skp1, skp1 + HN, pb, hbuf,
                                                g2, b2, abf1);
    } else {
      bgemm_kernel<0, true, 0, float><<<dim3(Dn / 128, gM), 256, 0, stream>>>(
          abf1, wp_t, pb, hbuf, hbuf, Mrows, Dn, Dn, Dn);
      ln_kernel<bf16><<<Mrows, 256, 0, stream>>>(hbuf, (size_t)Dn, g2, b2, abf1);
    }
    // fc1 + gelu -> abf2 (bf16 [M,DFF]) -- 128x256 8-wave kernel
    if (!useBig) run_convT(f1w, wtb, Dn, DFFn, 1, stream);
    wgemm_kernel<1, false, bf16><<<dim3(DFFn / 256, gM), 512, 0, stream>>>(
        abf1, w1_t, f1b, nullptr, abf2, Mrows, DFFn, Dn);
    // fc2 + residual: h += m @ f2w + f2b
    if (!useBig) run_convT(f2w, wtb, DFFn, Dn, 1, stream);
    if (useSplit) {
      bgemm_kernel<0, false, 1, float><<<dim3(Dn / 128, gM, 2), 256, 0, stream>>>(
          abf2, w2_t, f2b, nullptr, skp1, Mrows, Dn, DFFn, DFFn / 2);
      if (l + 1 < Ln) {
        const float* g1n = ln1_g + (size_t)(l + 1) * Dn;
        const float* b1n = ln1_b + (size_t)(l + 1) * Dn;
        redk_ln_kernel<<<Mrows, 256, 0, stream>>>(skp1, skp1 + HN, f2b, hbuf,
                                                  g1n, b1n, abf1);
      } else {
        redk_kernel<<<(Mrows * Dn / 4 + 255) / 256, 256, 0, stream>>>(
            skp1, skp1 + HN, f2b, hbuf, Mrows * Dn / 4);
      }
    } else {
      bgemm_kernel<0, true, 0, float><<<dim3(Dn / 128, gM), 256, 0, stream>>>(
          abf2, w2_t, f2b, hbuf, hbuf, Mrows, Dn, DFFn, DFFn);
    }
  }

  // head: post-LN of h[:,0,:] -> t1; tanh GEMV -> t2; logits GEMV -> out
  float* t1 = (float*)abf2;
  float* t2 = t1 + Bn * Dn;
  ln_kernel<float><<<Bn, 256, 0, stream>>>(hbuf, (size_t)Sn * Dn, post_g, post_b, t1);
  run_convT(h1_w, wtb, Dn, Dn, 1, stream);
  hgemv_kernel<2><<<Bn * Dn / 4, 256, 0, stream>>>(t1, wtb, h1_b, t2, Dn, Dn);
  run_convT(h2_w, wtb, Dn, OUTn, 1, stream);
  hgemv_kernel<0><<<Bn * OUTn / 4, 256, 0, stream>>>(t2, wtb, h2_b, out, OUTn, Dn);
}